// Round 16
// baseline (244.168 us; speedup 1.0000x reference)
//
#include <hip/hip_runtime.h>
#include <hip/hip_bf16.h>
#include <stdint.h>
#include <cstddef>

// Problem constants
#define BB  2
#define CC  512
#define TT  32
#define HWP 196   // H*W = 14*14
#define NH  8
#define KWIN 9
#define CID 64    // C / N
#define PPAD 4    // (K-1)/2
#define TP  40    // T + 2P
#define MTOT 12544  // BB*TT*HWP
#define NTOT 1536   // 3*CC (Q|K|V output channels)
#define VSLOT 224   // padded per-frame key slots (7*32)
#define LOG2E 1.44269504f

typedef unsigned short u16;
typedef unsigned int   u32;
typedef __attribute__((ext_vector_type(8))) short short8;
typedef __attribute__((ext_vector_type(4))) float floatx4;

__device__ __forceinline__ u16 f2bf(float f) {
    u32 u = __float_as_uint(f);
    u32 r = (u + 0x7fffu + ((u >> 16) & 1u)) >> 16;
    return (u16)r;
}
__device__ __forceinline__ u32 pack2bf(float a, float b) {
    return (u32)f2bf(a) | ((u32)f2bf(b) << 16);
}
// Truncating pack: [hi16(b) : hi16(a)] in one v_perm_b32.
__device__ __forceinline__ u32 packtrunc(float a, float b) {
    return __builtin_amdgcn_perm(__float_as_uint(b), __float_as_uint(a), 0x07060302u);
}
// Raw hardware exp2 (v_exp_f32, 1 ulp).
__device__ __forceinline__ float fexp2(float x) {
    return __builtin_amdgcn_exp2f(x);
}
// Async global->LDS, 16 B per lane. LDS dest is WAVE-UNIFORM base; HW writes
// lane l at base + l*16. Global src is per-lane.
__device__ __forceinline__ void gload16(const u16* g, u16* l) {
    __builtin_amdgcn_global_load_lds(
        (const __attribute__((address_space(1))) u32*)g,
        (__attribute__((address_space(3))) u32*)l, 16, 0, 0);
}

// ---------------------------------------------------------------------------
// Prep (fused): transpose_x (blocks 0..511) + W-concat/pad-fill (rest).
// Vectorized transpose branch (float4 in, uint4 out).
// ---------------------------------------------------------------------------
__global__ __launch_bounds__(256) void prep_transpose(
    const float* __restrict__ x, u16* __restrict__ xt,
    const float* __restrict__ Wq, const float* __restrict__ Wk,
    const float* __restrict__ Wv, u16* __restrict__ Wbf,
    const float* __restrict__ bk, const float* __restrict__ bv,
    u16* __restrict__ Kout, u16* __restrict__ Vtp)
{
    __shared__ float T[64 * 197];
    int bxg = blockIdx.x;
    int tid = threadIdx.x;

    if (bxg < BB * TT * 8) {
        // --- transpose x[b][c][t][p] fp32 -> xt[(b*T+t)*HW+p][c] bf16 ---
        int bx = bxg;
        int ct = bx & 7; bx >>= 3;
        int t = bx & 31;
        int b = bx >> 5;
        const float* src = x + ((size_t)(b * CC + ct * 64) * TT + t) * HWP;
        for (int i = tid; i < 64 * 49; i += 256) {
            int c = i / 49;
            int p4 = i - c * 49;
            float4 v = *(const float4*)(src + (size_t)c * (TT * HWP) + p4 * 4);
            float* Tp = &T[c * 197 + p4 * 4];
            Tp[0] = v.x; Tp[1] = v.y; Tp[2] = v.z; Tp[3] = v.w;
        }
        __syncthreads();
        u16* dst = xt + (size_t)((b * TT + t) * HWP) * CC + ct * 64;
        for (int i = tid; i < HWP * 8; i += 256) {
            int p = i >> 3;
            int c0 = (i & 7) * 8;
            u32 w[4];
            #pragma unroll
            for (int k = 0; k < 4; k++)
                w[k] = pack2bf(T[(c0 + 2 * k) * 197 + p],
                               T[(c0 + 2 * k + 1) * 197 + p]);
            *(uint4*)(dst + (size_t)p * CC + c0) = *(uint4*)w;
        }
        return;
    }

    // --- W concat fp32->bf16 + pad-frame fill for K and Vtp ---
    int id = (bxg - BB * TT * 8) * 256 + tid;
    const int wtot = NTOT * CC / 2;                // 393,216 u32 (W)
    const int kper = 2 * NH * 8 * HWP * 32;        // 802,816 u32 (K pads)
    const int vper = 2 * NH * 8 * 64 * (VSLOT/2);  // 917,504 u32 (Vtp pads)
    if (id < wtot) {
        int c2 = id & 255;
        int oc = id >> 8;
        int kind = oc >> 9;
        int idx = oc & 511;
        const float* src = (kind == 0 ? Wq : (kind == 1 ? Wk : Wv)) + (size_t)idx * CC + c2 * 2;
        ((u32*)Wbf)[id] = pack2bf(src[0], src[1]);
    } else if (id < wtot + kper) {
        int i = id - wtot;
        int ci2 = i & 31; i >>= 5;
        int p = i % HWP;  i /= HWP;
        int fr = i & 7;   i >>= 3;
        int head = i & 7;
        int b = i >> 3;
        int tp = fr < 4 ? fr : fr + 32;
        const float* bias = bk + head * CID + ci2 * 2;
        size_t addr = (((size_t)(b * NH + head) * TP + tp) * HWP + p) * 32 + ci2;
        ((u32*)Kout)[addr] = pack2bf(bias[0], bias[1]);
    } else if (id < wtot + kper + vper) {
        int i = id - wtot - kper;
        int s2 = i % (VSLOT/2); i /= (VSLOT/2);
        int ci = i & 63; i >>= 6;
        int fr = i & 7;  i >>= 3;
        int head = i & 7;
        int b = i >> 3;
        int tp = fr < 4 ? fr : fr + 32;
        float bias = bv[head * CID + ci];
        size_t addr = (((size_t)(b * NH + head) * TP + tp) * 64 + ci) * (VSLOT/2) + s2;
        ((u32*)Vtp)[addr] = pack2bf(bias, bias);   // whole row = bias[ci]
    }
}

// ---------------------------------------------------------------------------
// MFMA projection GEMM v5: gload_lds staging (R12-verified) + coalesced Q/K
// epilogue. kind = nb>>1 is block-uniform; each Q/K output row (m, head) is
// 128 B contiguous. After the K-loop, the staging LDS is dead -> each wave
// re-stages its 64x64 tile (bias+scale applied) into a shared 34.8 KB region
// (two wm-phases) and writes full 128 B rows as uint4: 8 coalesced store
// instrs/wave instead of 64 scalar u16 scatters. V blocks keep the verified
// slot-permuted scatter path (R14).
// ---------------------------------------------------------------------------
__global__ __launch_bounds__(512) void proj_gemm2(
    const u16* __restrict__ xt, const u16* __restrict__ Wbf,
    const float* __restrict__ bq, const float* __restrict__ bk,
    const float* __restrict__ bv,
    u16* __restrict__ Qout, u16* __restrict__ Kout, u16* __restrict__ Vtp)
{
    __shared__ union {
        struct { u16 A[128 * 64]; u16 B[256 * 64]; } g;   // 48 KB staging
        u16 out[4][64][68];                                // 34.8 KB epilogue
    } s;

    int bx = blockIdx.x;
    int nb = bx % 6;
    int mt = bx / 6;
    int tid = threadIdx.x;
    int wave = tid >> 6, lane = tid & 63, quad = lane >> 4, l15 = lane & 15;
    int wm = wave >> 2, wn = wave & 3;
    int mbase = mt * 128 + wm * 64;
    int nbase = nb * 256 + wn * 64;

    int lr = lane >> 3;                        // row within 8-row group
    int sw = ((lane & 7) * 8) ^ (lr << 3);     // swizzled u16 col (source side)

    floatx4 acc[4][4];
    #pragma unroll
    for (int ms = 0; ms < 4; ms++)
        #pragma unroll
        for (int ns = 0; ns < 4; ns++)
            acc[ms][ns] = (floatx4){0.f, 0.f, 0.f, 0.f};

    const u16* abase = xt + (size_t)(mt * 128) * CC;
    const u16* bbase = Wbf + (size_t)(nb * 256) * CC;

    for (int kc = 0; kc < 8; kc++) {
        __syncthreads();   // previous tile's LDS reads complete
        #pragma unroll
        for (int i = 0; i < 2; i++) {
            int rbase = wave * 16 + i * 8;
            gload16(abase + (size_t)(rbase + lr) * CC + kc * 64 + sw,
                    &s.g.A[rbase * 64]);
        }
        #pragma unroll
        for (int i = 0; i < 4; i++) {
            int rbase = wave * 32 + i * 8;
            gload16(bbase + (size_t)(rbase + lr) * CC + kc * 64 + sw,
                    &s.g.B[rbase * 64]);
        }
        __syncthreads();   // compiler drains vmcnt before the barrier

        #pragma unroll
        for (int kk = 0; kk < 2; kk++) {
            int swr = (kk * 32 + quad * 8) ^ ((l15 & 7) << 3);   // read swizzle
            short8 af[4], bf[4];
            #pragma unroll
            for (int ms = 0; ms < 4; ms++)
                af[ms] = *(const short8*)&s.g.A[(wm * 64 + ms * 16 + l15) * 64 + swr];
            #pragma unroll
            for (int ns = 0; ns < 4; ns++)
                bf[ns] = *(const short8*)&s.g.B[(wn * 64 + ns * 16 + l15) * 64 + swr];
            #pragma unroll
            for (int ms = 0; ms < 4; ms++)
                #pragma unroll
                for (int ns = 0; ns < 4; ns++)
                    acc[ms][ns] = __builtin_amdgcn_mfma_f32_16x16x32_bf16(
                        af[ms], bf[ns], acc[ms][ns], 0, 0, 0);
        }
    }

    float biasv[4];
    #pragma unroll
    for (int ns = 0; ns < 4; ns++) {
        int n = nbase + ns * 16 + l15;
        int kind = n >> 9;
        int idx = n & 511;
        const float* bpb = kind == 0 ? bq : (kind == 1 ? bk : bv);
        biasv[ns] = bpb[idx];
    }

    int kindb = nb >> 1;   // block-uniform: 0 Q, 1 K, 2 V
    if (kindb < 2) {
        // -------- coalesced Q/K epilogue --------
        int head = (nb & 1) * 4 + wn;          // idx>>6 for this wave's n-range
        float scale = kindb == 0 ? LOG2E : 1.0f;
        u16* outp = kindb == 0 ? Qout : Kout;
        __syncthreads();                       // all staging-LDS reads done
        #pragma unroll
        for (int ph = 0; ph < 2; ph++) {
            if (wm == ph) {
                // stage this wave's 64x64 tile (+bias, x scale)
                #pragma unroll
                for (int ms = 0; ms < 4; ms++)
                    #pragma unroll
                    for (int r = 0; r < 4; r++) {
                        int mp = ms * 16 + quad * 4 + r;
                        #pragma unroll
                        for (int ns = 0; ns < 4; ns++)
                            s.out[wn][mp][ns * 16 + l15] =
                                f2bf((acc[ms][ns][r] + biasv[ns]) * scale);
                    }
                // coalesced 128B-row stores: 8 rows/instr, 16B/lane
                #pragma unroll
                for (int i = 0; i < 8; i++) {
                    int mp = i * 8 + (lane >> 3);
                    int m = mbase + mp;
                    int b = m / (TT * HWP);
                    int rem = m - b * (TT * HWP);
                    int t = rem / HWP;
                    int p = rem - t * HWP;
                    size_t row = kindb == 0
                        ? (((size_t)(b * NH + head) * TT + t) * HWP + p)
                        : (((size_t)(b * NH + head) * TP + (t + PPAD)) * HWP + p);
                    *(uint4*)(outp + row * CID + (lane & 7) * 8) =
                        *(const uint4*)&s.out[wn][mp][(lane & 7) * 8];
                }
            }
            __syncthreads();
        }
    } else {
        // -------- V epilogue (R14-verified slot-permuted scatter) --------
        #pragma unroll
        for (int ms = 0; ms < 4; ms++) {
            #pragma unroll
            for (int r = 0; r < 4; r++) {
                int m = mbase + ms * 16 + quad * 4 + r;
                int b = m / (TT * HWP);
                int rem = m - b * (TT * HWP);
                int t = rem / HWP;
                int p = rem - t * HWP;
                int slot_p = (p & ~31) | (p & 3) | (((p >> 4) & 1) << 2)
                           | (((p >> 2) & 1) << 3) | (((p >> 3) & 1) << 4);
                #pragma unroll
                for (int ns = 0; ns < 4; ns++) {
                    int n = nbase + ns * 16 + l15;
                    int idx = n & 511;
                    int head = idx >> 6;
                    int ci = idx & 63;
                    float val = acc[ms][ns][r] + biasv[ns];
                    Vtp[(((size_t)(b * NH + head) * TP + (t + PPAD)) * 64 + ci) * VSLOT + slot_p]
                        = f2bf(val);
                }
            }
        }
    }
}

// ---------------------------------------------------------------------------
// MFMA flash attention v13 (R15-verified, UNCHANGED): dead-tile-free, 3 main
// tiles/wave + frame-distributed tile 12, direct-global K/V, depth-2
// prefetch, barrier-free main loop.
// ---------------------------------------------------------------------------
__global__ __launch_bounds__(256, 1) void attn_mfma4(
    const float* __restrict__ x,
    const u16* __restrict__ Qb, const u16* __restrict__ Kb,
    const u16* __restrict__ Vtp, float* __restrict__ zout)
{
    __shared__ float eT[192 * 66];      // rows 0..191 (50,688 B)
    __shared__ float eT12[4][4][66];    // tile-12 partials [wave][rr][ci]
    __shared__ float ls12[4][4];        // tile-12 l partials [wave][rr]

    int i = blockIdx.x;
    int xcd = i & 7;
    int r = i >> 3;                        // 0..63
    int slab = ((r >= 32) ? 8 : 0) | xcd;  // slab pinned to one XCD
    int t = r & 31;
    int b = slab >> 3, n = slab & 7;

    int tid = threadIdx.x;
    int wave = tid >> 6;
    int lane = tid & 63;
    int quad = lane >> 4, l15 = lane & 15;

    const u16* kfr0 = Kb + (size_t)slab * (TP * HWP) * CID;
    const u16* vslab = Vtp + (size_t)slab * (TP * 64 * VSLOT);
    const float tmask = (quad == 0) ? 1.0f : 0.0f;

    // Q B-frags: main tiles tg = wave + 4*j (j=0..2, rows <= 191, no clamp)
    short8 qf[3][2];
    #pragma unroll
    for (int j = 0; j < 3; j++) {
        int qrow = (wave + 4 * j) * 16 + l15;
        const u16* qp = Qb + ((size_t)(slab * TT + t) * HWP + qrow) * CID;
        qf[j][0] = *(const short8*)(qp + quad * 8);
        qf[j][1] = *(const short8*)(qp + 32 + quad * 8);
    }
    // Tile 12 (rows 192..195 valid; clamp dups row 195 for l15 > 3)
    short8 qf12[2];
    {
        int qrow = 192 + l15;
        qrow = qrow < HWP ? qrow : (HWP - 1);
        const u16* qp = Qb + ((size_t)(slab * TT + t) * HWP + qrow) * CID;
        qf12[0] = *(const short8*)(qp + quad * 8);
        qf12[1] = *(const short8*)(qp + 32 + quad * 8);
    }

    floatx4 acc[3][4];
    floatx4 accl[3];
    floatx4 acc12[4];
    floatx4 accl12;
    #pragma unroll
    for (int j = 0; j < 3; j++) {
        #pragma unroll
        for (int cg = 0; cg < 4; cg++) acc[j][cg] = (floatx4){0.f, 0.f, 0.f, 0.f};
        accl[j] = (floatx4){0.f, 0.f, 0.f, 0.f};
    }
    #pragma unroll
    for (int cg = 0; cg < 4; cg++) acc12[cg] = (floatx4){0.f, 0.f, 0.f, 0.f};
    accl12 = (floatx4){0.f, 0.f, 0.f, 0.f};

    union { u32 w[4]; short8 s; } ones;
    ones.w[0] = 0x3F803F80u; ones.w[1] = 0x3F803F80u;
    ones.w[2] = 0x3F803F80u; ones.w[3] = 0x3F803F80u;

    #define KLOAD(c, D00, D01, D10, D11) do {                                    \
        const u16* a0_ = kfr0 + (size_t)(rbase + (c) * 32 + l15) * CID + quad * 8;\
        const u16* a1_ = a0_ + (size_t)16 * CID;                                 \
        D00 = *(const short8*)a0_;  D01 = *(const short8*)(a0_ + 32);            \
        D10 = *(const short8*)a1_;  D11 = *(const short8*)(a1_ + 32);            \
    } while (0)

    #define KLOADTAIL(D00, D01) do {                                             \
        int g_ = rbase + 192 + l15;                                              \
        g_ = g_ < (TP * HWP - 1) ? g_ : (TP * HWP - 1);                          \
        const u16* a0_ = kfr0 + (size_t)g_ * CID + quad * 8;                     \
        D00 = *(const short8*)a0_;  D01 = *(const short8*)(a0_ + 32);            \
    } while (0)

    #define VLOAD(c, D0, D1, D2, D3) do {                                        \
        const u16* v_ = vfr + l15 * VSLOT + (c) * 32 + quad * 8;                 \
        D0 = *(const short8*)v_;                                                 \
        D1 = *(const short8*)(v_ + 16 * VSLOT);                                  \
        D2 = *(const short8*)(v_ + 32 * VSLOT);                                  \
        D3 = *(const short8*)(v_ + 48 * VSLOT);                                  \
    } while (0)

    #define CHUNK_ONE(Q0, Q1, ACC, ACCL, K00, K01, K10, K11, V0, V1, V2, V3) do {\
        floatx4 sc0 = (floatx4){0.f, 0.f, 0.f, 0.f};                             \
        sc0 = __builtin_amdgcn_mfma_f32_16x16x32_bf16(K00, Q0, sc0, 0, 0, 0);    \
        sc0 = __builtin_amdgcn_mfma_f32_16x16x32_bf16(K01, Q1, sc0, 0, 0, 0);    \
        floatx4 sc1 = (floatx4){0.f, 0.f, 0.f, 0.f};                             \
        sc1 = __builtin_amdgcn_mfma_f32_16x16x32_bf16(K10, Q0, sc1, 0, 0, 0);    \
        sc1 = __builtin_amdgcn_mfma_f32_16x16x32_bf16(K11, Q1, sc1, 0, 0, 0);    \
        union { u32 w[4]; short8 s; } pf;                                        \
        pf.w[0] = packtrunc(fexp2(sc0[0]), fexp2(sc0[1]));                       \
        pf.w[1] = packtrunc(fexp2(sc0[2]), fexp2(sc0[3]));                       \
        pf.w[2] = packtrunc(fexp2(sc1[0]), fexp2(sc1[1]));                       \
        pf.w[3] = packtrunc(fexp2(sc1[2]), fexp2(sc1[3]));                       \
        ACC[0] = __builtin_amdgcn_mfma_f32_16x16x32_bf16(pf.s, V0, ACC[0], 0, 0, 0); \
        ACC[1] = __builtin_amdgcn_mfma_f32_16x16x32_bf16(pf.s, V1, ACC[1], 0, 0, 0); \
        ACC[2] = __builtin_amdgcn_mfma_f32_16x16x32_bf16(pf.s, V2, ACC[2], 0, 0, 0); \
        ACC[3] = __builtin_amdgcn_mfma_f32_16x16x32_bf16(pf.s, V3, ACC[3], 0, 0, 0); \
        ACCL   = __builtin_amdgcn_mfma_f32_16x16x32_bf16(pf.s, ones.s, ACCL, 0, 0, 0); \
    } while (0)

    #define TAIL_ONE(Q0, Q1, ACC, ACCL, K00, K01, V0, V1, V2, V3) do {           \
        floatx4 sc0 = (floatx4){0.f, 0.f, 0.f, 0.f};                             \
        sc0 = __builtin_amdgcn_mfma_f32_16x16x32_bf16(K00, Q0, sc0, 0, 0, 0);    \
        sc0 = __builtin_amdgcn_mfma_f32_16x16x32_bf16(K01, Q1, sc0, 0, 0, 0);    \
        union { u32 w[4]; short8 s; } pf;                                        \
        pf.w[0] = packtrunc(fexp2(sc0[0]) * tmask, fexp2(sc0[1]) * tmask);       \
        pf.w[1] = packtrunc(fexp2(sc0[2]) * tmask, fexp2(sc0[3]) * tmask);       \
        pf.w[2] = 0u;                                                            \
        pf.w[3] = 0u;                                                            \
        ACC[0] = __builtin_amdgcn_mfma_f32_16x16x32_bf16(pf.s, V0, ACC[0], 0, 0, 0); \
        ACC[1] = __builtin_amdgcn_mfma_f32_16x16x32_bf16(pf.s, V1, ACC[1], 0, 0, 0); \
        ACC[2] = __builtin_amdgcn_mfma_f32_16x16x32_bf16(pf.s, V2, ACC[2], 0, 0, 0); \
        ACC[3] = __builtin_amdgcn_mfma_f32_16x16x32_bf16(pf.s, V3, ACC[3], 0, 0, 0); \
        ACCL   = __builtin_amdgcn_mfma_f32_16x16x32_bf16(pf.s, ones.s, ACCL, 0, 0, 0); \
    } while (0)

    #define CHUNK_FULL(K00, K01, K10, K11, V0, V1, V2, V3) do {                  \
        _Pragma("unroll")                                                        \
        for (int j = 0; j < 3; j++)                                              \
            CHUNK_ONE(qf[j][0], qf[j][1], acc[j], accl[j],                       \
                      K00, K01, K10, K11, V0, V1, V2, V3);                       \
        if (do12)                                                                \
            CHUNK_ONE(qf12[0], qf12[1], acc12, accl12,                           \
                      K00, K01, K10, K11, V0, V1, V2, V3);                       \
    } while (0)

    #define CHUNK_TAIL(K00, K01, V0, V1, V2, V3) do {                            \
        _Pragma("unroll")                                                        \
        for (int j = 0; j < 3; j++)                                              \
            TAIL_ONE(qf[j][0], qf[j][1], acc[j], accl[j],                        \
                     K00, K01, V0, V1, V2, V3);                                  \
        if (do12)                                                                \
            TAIL_ONE(qf12[0], qf12[1], acc12, accl12,                            \
                     K00, K01, V0, V1, V2, V3);                                  \
    } while (0)

    for (int f = 0; f < KWIN; f++) {
        int rbase = (t + f) * HWP;
        const u16* vfr = vslab + (size_t)(t + f) * (64 * VSLOT);
        bool do12 = ((f & 3) == wave);   // frame-distributed tile 12

        short8 ka00, ka01, ka10, ka11, va0, va1, va2, va3;
        short8 kb00, kb01, kb10, kb11, vb0, vb1, vb2, vb3;
        short8 kc00, kc01, kc10, kc11, vc0, vc1, vc2, vc3;

        // Depth-2 pipeline: 3 chunk-loads in flight before first compute.
        KLOAD(0, ka00, ka01, ka10, ka11);  VLOAD(0, va0, va1, va2, va3);
        KLOAD(1, kb00, kb01, kb10, kb11);  VLOAD(1, vb0, vb1, vb2, vb3);
        KLOAD(2, kc00, kc01, kc10, kc11);  VLOAD(2, vc0, vc1, vc2, vc3);
        CHUNK_FULL(ka00, ka01, ka10, ka11, va0, va1, va2, va3);      // c=0
        KLOAD(3, ka00, ka01, ka10, ka11);  VLOAD(3, va0, va1, va2, va3);
        CHUNK_FULL(kb00, kb01, kb10, kb11, vb0, vb1, vb2, vb3);      // c=1
        KLOAD(4, kb00, kb01, kb10, kb11);  VLOAD(4, vb0, vb1, vb2, vb3);
        CHUNK_FULL(kc00, kc01, kc10, kc11, vc0, vc1, vc2, vc3);      // c=2
        KLOAD(5, kc00, kc01, kc10, kc11);  VLOAD(5, vc0, vc1, vc2, vc3);
        CHUNK_FULL(ka00, ka01, ka10, ka11, va0, va1, va2, va3);      // c=3
        KLOADTAIL(ka00, ka01);             VLOAD(6, va0, va1, va2, va3);
        CHUNK_FULL(kb00, kb01, kb10, kb11, vb0, vb1, vb2, vb3);      // c=4
        CHUNK_FULL(kc00, kc01, kc10, kc11, vc0, vc1, vc2, vc3);      // c=5
        CHUNK_TAIL(ka00, ka01, va0, va1, va2, va3);                  // keys 192..195
    }

    #undef KLOAD
    #undef KLOADTAIL
    #undef VLOAD
    #undef CHUNK_ONE
    #undef TAIL_ONE
    #undef CHUNK_FULL
    #undef CHUNK_TAIL

    // Epilogue: main tiles normalized into eT (rows 0..191); tile-12 raw
    // partials into eT12/ls12; combine + normalize at store.
    #pragma unroll
    for (int j = 0; j < 3; j++) {
        int tg = wave + 4 * j;
        float il[4];
        #pragma unroll
        for (int rr = 0; rr < 4; rr++) il[rr] = 1.0f / accl[j][rr];
        #pragma unroll
        for (int cg = 0; cg < 4; cg++) {
            #pragma unroll
            for (int rr = 0; rr < 4; rr++) {
                int p = tg * 16 + quad * 4 + rr;     // always < 192
                eT[p * 66 + cg * 16 + l15] = acc[j][cg][rr] * il[rr];
            }
        }
    }
    if (quad == 0) {
        #pragma unroll
        for (int rr = 0; rr < 4; rr++) {
            #pragma unroll
            for (int cg = 0; cg < 4; cg++)
                eT12[wave][rr][cg * 16 + l15] = acc12[cg][rr];
            if (l15 == 0) ls12[wave][rr] = accl12[rr];
        }
    }
    __syncthreads();

    if (tid < HWP) {
        size_t base = ((size_t)(b * CC + n * CID) * TT + t) * HWP + tid;
        if (tid < 192) {
            for (int ci = 0; ci < 64; ci++) {
                size_t a = base + (size_t)ci * (TT * HWP);
                zout[a] = eT[tid * 66 + ci] + x[a];
            }
        } else {
            int rr = tid - 192;
            float l = ls12[0][rr] + ls12[1][rr] + ls12[2][rr] + ls12[3][rr];
            float il = 1.0f / l;
            for (int ci = 0; ci < 64; ci++) {
                size_t a = base + (size_t)ci * (TT * HWP);
                float v = (eT12[0][rr][ci] + eT12[1][rr][ci]
                         + eT12[2][rr][ci] + eT12[3][rr][ci]) * il;
                zout[a] = v + x[a];
            }
        }
    }
}

// ---------------------------------------------------------------------------
extern "C" void kernel_launch(void* const* d_in, const int* in_sizes, int n_in,
                              void* d_out, int out_size, void* d_ws, size_t ws_size,
                              hipStream_t stream) {
    const float* x  = (const float*)d_in[0];
    const float* Wq = (const float*)d_in[1];
    const float* bq = (const float*)d_in[2];
    const float* Wk = (const float*)d_in[3];
    const float* bk = (const float*)d_in[4];
    const float* Wv = (const float*)d_in[5];
    const float* bv = (const float*)d_in[6];
    float* z = (float*)d_out;

    // ws (bf16): Q, K, Vtp, W (~48.8 MB, proven). d_out scratch: xt only.
    const size_t qElems   = (size_t)BB * NH * TT * HWP * CID;   // 6,422,528
    const size_t kElems   = (size_t)BB * NH * TP * HWP * CID;   // 8,028,160
    const size_t vtpElems = (size_t)BB * NH * TP * 64 * VSLOT;  // 9,175,040

    u16* Qw  = (u16*)d_ws;
    u16* Kw  = Qw + qElems;
    u16* Vtp = Kw + kElems;
    u16* Wb  = Vtp + vtpElems;
    u16* Xt  = (u16*)d_out;

    {
        const int wtot = NTOT * CC / 2;
        const int kper = 2 * NH * 8 * HWP * 32;
        const int vper = 2 * NH * 8 * 64 * (VSLOT / 2);
        const int prepBlocks = (wtot + kper + vper + 255) / 256;   // 8256
        prep_transpose<<<BB * TT * 8 + prepBlocks, 256, 0, stream>>>(
            x, Xt, Wq, Wk, Wv, Wb, bk, bv, Kw, Vtp);
    }
    // 98 m-tiles x 6 n-tiles, 512 threads; gload_lds staging, coalesced
    // Q/K epilogue, fused V write.
    proj_gemm2<<<98 * 6, 512, 0, stream>>>(Xt, Wb, bq, bk, bv, Qw, Kw, Vtp);
    // 16 slabs * 32 t, 4 waves/block, XCD-swizzled; 512 blocks.
    attn_mfma4<<<512, 256, 0, stream>>>(x, Qw, Kw, Vtp, z);
}

// Round 17
// 239.736 us; speedup vs baseline: 1.0185x; 1.0185x over previous
//
#include <hip/hip_runtime.h>
#include <hip/hip_bf16.h>
#include <stdint.h>
#include <cstddef>

// Problem constants
#define BB  2
#define CC  512
#define TT  32
#define HWP 196   // H*W = 14*14
#define NH  8
#define KWIN 9
#define CID 64    // C / N
#define PPAD 4    // (K-1)/2
#define TP  40    // T + 2P
#define MTOT 12544  // BB*TT*HWP
#define NTOT 1536   // 3*CC (Q|K|V output channels)
#define VSLOT 224   // padded per-frame key slots (7*32)
#define LOG2E 1.44269504f

typedef unsigned short u16;
typedef unsigned int   u32;
typedef __attribute__((ext_vector_type(8))) short short8;
typedef __attribute__((ext_vector_type(4))) float floatx4;

__device__ __forceinline__ u16 f2bf(float f) {
    u32 u = __float_as_uint(f);
    u32 r = (u + 0x7fffu + ((u >> 16) & 1u)) >> 16;
    return (u16)r;
}
__device__ __forceinline__ u32 pack2bf(float a, float b) {
    return (u32)f2bf(a) | ((u32)f2bf(b) << 16);
}
// Truncating pack: [hi16(b) : hi16(a)] in one v_perm_b32.
__device__ __forceinline__ u32 packtrunc(float a, float b) {
    return __builtin_amdgcn_perm(__float_as_uint(b), __float_as_uint(a), 0x07060302u);
}
// Raw hardware exp2 (v_exp_f32, 1 ulp).
__device__ __forceinline__ float fexp2(float x) {
    return __builtin_amdgcn_exp2f(x);
}
// Async global->LDS, 16 B per lane. LDS dest is WAVE-UNIFORM base; HW writes
// lane l at base + l*16. Global src is per-lane.
__device__ __forceinline__ void gload16(const u16* g, u16* l) {
    __builtin_amdgcn_global_load_lds(
        (const __attribute__((address_space(1))) u32*)g,
        (__attribute__((address_space(3))) u32*)l, 16, 0, 0);
}

// ---------------------------------------------------------------------------
// Prep (fused): transpose_x (blocks 0..511) + W-concat/pad-fill (rest).
// Vectorized transpose branch (float4 in, uint4 out).
// ---------------------------------------------------------------------------
__global__ __launch_bounds__(256) void prep_transpose(
    const float* __restrict__ x, u16* __restrict__ xt,
    const float* __restrict__ Wq, const float* __restrict__ Wk,
    const float* __restrict__ Wv, u16* __restrict__ Wbf,
    const float* __restrict__ bk, const float* __restrict__ bv,
    u16* __restrict__ Kout, u16* __restrict__ Vtp)
{
    __shared__ float T[64 * 197];
    int bxg = blockIdx.x;
    int tid = threadIdx.x;

    if (bxg < BB * TT * 8) {
        // --- transpose x[b][c][t][p] fp32 -> xt[(b*T+t)*HW+p][c] bf16 ---
        int bx = bxg;
        int ct = bx & 7; bx >>= 3;
        int t = bx & 31;
        int b = bx >> 5;
        const float* src = x + ((size_t)(b * CC + ct * 64) * TT + t) * HWP;
        for (int i = tid; i < 64 * 49; i += 256) {
            int c = i / 49;
            int p4 = i - c * 49;
            float4 v = *(const float4*)(src + (size_t)c * (TT * HWP) + p4 * 4);
            float* Tp = &T[c * 197 + p4 * 4];
            Tp[0] = v.x; Tp[1] = v.y; Tp[2] = v.z; Tp[3] = v.w;
        }
        __syncthreads();
        u16* dst = xt + (size_t)((b * TT + t) * HWP) * CC + ct * 64;
        for (int i = tid; i < HWP * 8; i += 256) {
            int p = i >> 3;
            int c0 = (i & 7) * 8;
            u32 w[4];
            #pragma unroll
            for (int k = 0; k < 4; k++)
                w[k] = pack2bf(T[(c0 + 2 * k) * 197 + p],
                               T[(c0 + 2 * k + 1) * 197 + p]);
            *(uint4*)(dst + (size_t)p * CC + c0) = *(uint4*)w;
        }
        return;
    }

    // --- W concat fp32->bf16 + pad-frame fill for K and Vtp ---
    int id = (bxg - BB * TT * 8) * 256 + tid;
    const int wtot = NTOT * CC / 2;                // 393,216 u32 (W)
    const int kper = 2 * NH * 8 * HWP * 32;        // 802,816 u32 (K pads)
    const int vper = 2 * NH * 8 * 64 * (VSLOT/2);  // 917,504 u32 (Vtp pads)
    if (id < wtot) {
        int c2 = id & 255;
        int oc = id >> 8;
        int kind = oc >> 9;
        int idx = oc & 511;
        const float* src = (kind == 0 ? Wq : (kind == 1 ? Wk : Wv)) + (size_t)idx * CC + c2 * 2;
        ((u32*)Wbf)[id] = pack2bf(src[0], src[1]);
    } else if (id < wtot + kper) {
        int i = id - wtot;
        int ci2 = i & 31; i >>= 5;
        int p = i % HWP;  i /= HWP;
        int fr = i & 7;   i >>= 3;
        int head = i & 7;
        int b = i >> 3;
        int tp = fr < 4 ? fr : fr + 32;
        const float* bias = bk + head * CID + ci2 * 2;
        size_t addr = (((size_t)(b * NH + head) * TP + tp) * HWP + p) * 32 + ci2;
        ((u32*)Kout)[addr] = pack2bf(bias[0], bias[1]);
    } else if (id < wtot + kper + vper) {
        int i = id - wtot - kper;
        int s2 = i % (VSLOT/2); i /= (VSLOT/2);
        int ci = i & 63; i >>= 6;
        int fr = i & 7;  i >>= 3;
        int head = i & 7;
        int b = i >> 3;
        int tp = fr < 4 ? fr : fr + 32;
        float bias = bv[head * CID + ci];
        size_t addr = (((size_t)(b * NH + head) * TP + tp) * 64 + ci) * (VSLOT/2) + s2;
        ((u32*)Vtp)[addr] = pack2bf(bias, bias);   // whole row = bias[ci]
    }
}

// ---------------------------------------------------------------------------
// MFMA projection GEMM v4 (R14/R15-verified): gload_lds staging + fused V
// epilogue writing Vtp directly via inverse slot permutation. (R16's
// coalesced Q/K epilogue reverted: measured slightly negative.)
// ---------------------------------------------------------------------------
__global__ __launch_bounds__(512) void proj_gemm2(
    const u16* __restrict__ xt, const u16* __restrict__ Wbf,
    const float* __restrict__ bq, const float* __restrict__ bk,
    const float* __restrict__ bv,
    u16* __restrict__ Qout, u16* __restrict__ Kout, u16* __restrict__ Vtp)
{
    __shared__ u16 sA[128 * 64];   // 16 KB linear (swizzled content)
    __shared__ u16 sB[256 * 64];   // 32 KB

    int bx = blockIdx.x;
    int nb = bx % 6;
    int mt = bx / 6;
    int tid = threadIdx.x;
    int wave = tid >> 6, lane = tid & 63, quad = lane >> 4, l15 = lane & 15;
    int wm = wave >> 2, wn = wave & 3;
    int mbase = mt * 128 + wm * 64;
    int nbase = nb * 256 + wn * 64;

    int lr = lane >> 3;                        // row within 8-row group
    int sw = ((lane & 7) * 8) ^ (lr << 3);     // swizzled u16 col (source side)

    floatx4 acc[4][4];
    #pragma unroll
    for (int ms = 0; ms < 4; ms++)
        #pragma unroll
        for (int ns = 0; ns < 4; ns++)
            acc[ms][ns] = (floatx4){0.f, 0.f, 0.f, 0.f};

    const u16* abase = xt + (size_t)(mt * 128) * CC;
    const u16* bbase = Wbf + (size_t)(nb * 256) * CC;

    for (int kc = 0; kc < 8; kc++) {
        __syncthreads();   // previous tile's LDS reads complete
        #pragma unroll
        for (int i = 0; i < 2; i++) {
            int rbase = wave * 16 + i * 8;
            gload16(abase + (size_t)(rbase + lr) * CC + kc * 64 + sw,
                    &sA[rbase * 64]);
        }
        #pragma unroll
        for (int i = 0; i < 4; i++) {
            int rbase = wave * 32 + i * 8;
            gload16(bbase + (size_t)(rbase + lr) * CC + kc * 64 + sw,
                    &sB[rbase * 64]);
        }
        __syncthreads();   // compiler drains vmcnt before the barrier

        #pragma unroll
        for (int kk = 0; kk < 2; kk++) {
            int swr = (kk * 32 + quad * 8) ^ ((l15 & 7) << 3);   // read swizzle
            short8 af[4], bf[4];
            #pragma unroll
            for (int ms = 0; ms < 4; ms++)
                af[ms] = *(const short8*)&sA[(wm * 64 + ms * 16 + l15) * 64 + swr];
            #pragma unroll
            for (int ns = 0; ns < 4; ns++)
                bf[ns] = *(const short8*)&sB[(wn * 64 + ns * 16 + l15) * 64 + swr];
            #pragma unroll
            for (int ms = 0; ms < 4; ms++)
                #pragma unroll
                for (int ns = 0; ns < 4; ns++)
                    acc[ms][ns] = __builtin_amdgcn_mfma_f32_16x16x32_bf16(
                        af[ms], bf[ns], acc[ms][ns], 0, 0, 0);
        }
    }

    float biasv[4];
    #pragma unroll
    for (int ns = 0; ns < 4; ns++) {
        int n = nbase + ns * 16 + l15;
        int kind = n >> 9;
        int idx = n & 511;
        const float* bpb = kind == 0 ? bq : (kind == 1 ? bk : bv);
        biasv[ns] = bpb[idx];
    }

    #pragma unroll
    for (int ms = 0; ms < 4; ms++) {
        #pragma unroll
        for (int r = 0; r < 4; r++) {
            int m = mbase + ms * 16 + quad * 4 + r;
            int b = m / (TT * HWP);
            int rem = m - b * (TT * HWP);
            int t = rem / HWP;
            int p = rem - t * HWP;
            // inverse slot permutation for the fused Vtp write
            int slot_p = (p & ~31) | (p & 3) | (((p >> 4) & 1) << 2)
                       | (((p >> 2) & 1) << 3) | (((p >> 3) & 1) << 4);
            #pragma unroll
            for (int ns = 0; ns < 4; ns++) {
                int n = nbase + ns * 16 + l15;
                int kind = n >> 9;          // uniform across block (kind = nb>>1)
                int idx = n & 511;
                int head = idx >> 6;
                int ci = idx & 63;
                float val = acc[ms][ns][r] + biasv[ns];
                if (kind == 0) {
                    Qout[(((size_t)(b * NH + head) * TT + t) * HWP + p) * CID + ci]
                        = f2bf(val * LOG2E);
                } else if (kind == 1) {
                    Kout[(((size_t)(b * NH + head) * TP + (t + PPAD)) * HWP + p) * CID + ci]
                        = f2bf(val);
                } else {
                    Vtp[(((size_t)(b * NH + head) * TP + (t + PPAD)) * 64 + ci) * VSLOT + slot_p]
                        = f2bf(val);
                }
            }
        }
    }
}

// ---------------------------------------------------------------------------
// MFMA flash attention v13 (R15-verified, UNCHANGED): dead-tile-free, 3 main
// tiles/wave + frame-distributed tile 12, direct-global K/V, depth-2
// prefetch, barrier-free main loop.
// ---------------------------------------------------------------------------
__global__ __launch_bounds__(256, 1) void attn_mfma4(
    const float* __restrict__ x,
    const u16* __restrict__ Qb, const u16* __restrict__ Kb,
    const u16* __restrict__ Vtp, float* __restrict__ zout)
{
    __shared__ float eT[192 * 66];      // rows 0..191 (50,688 B)
    __shared__ float eT12[4][4][66];    // tile-12 partials [wave][rr][ci]
    __shared__ float ls12[4][4];        // tile-12 l partials [wave][rr]

    int i = blockIdx.x;
    int xcd = i & 7;
    int r = i >> 3;                        // 0..63
    int slab = ((r >= 32) ? 8 : 0) | xcd;  // slab pinned to one XCD
    int t = r & 31;
    int b = slab >> 3, n = slab & 7;

    int tid = threadIdx.x;
    int wave = tid >> 6;
    int lane = tid & 63;
    int quad = lane >> 4, l15 = lane & 15;

    const u16* kfr0 = Kb + (size_t)slab * (TP * HWP) * CID;
    const u16* vslab = Vtp + (size_t)slab * (TP * 64 * VSLOT);
    const float tmask = (quad == 0) ? 1.0f : 0.0f;

    // Q B-frags: main tiles tg = wave + 4*j (j=0..2, rows <= 191, no clamp)
    short8 qf[3][2];
    #pragma unroll
    for (int j = 0; j < 3; j++) {
        int qrow = (wave + 4 * j) * 16 + l15;
        const u16* qp = Qb + ((size_t)(slab * TT + t) * HWP + qrow) * CID;
        qf[j][0] = *(const short8*)(qp + quad * 8);
        qf[j][1] = *(const short8*)(qp + 32 + quad * 8);
    }
    // Tile 12 (rows 192..195 valid; clamp dups row 195 for l15 > 3)
    short8 qf12[2];
    {
        int qrow = 192 + l15;
        qrow = qrow < HWP ? qrow : (HWP - 1);
        const u16* qp = Qb + ((size_t)(slab * TT + t) * HWP + qrow) * CID;
        qf12[0] = *(const short8*)(qp + quad * 8);
        qf12[1] = *(const short8*)(qp + 32 + quad * 8);
    }

    floatx4 acc[3][4];
    floatx4 accl[3];
    floatx4 acc12[4];
    floatx4 accl12;
    #pragma unroll
    for (int j = 0; j < 3; j++) {
        #pragma unroll
        for (int cg = 0; cg < 4; cg++) acc[j][cg] = (floatx4){0.f, 0.f, 0.f, 0.f};
        accl[j] = (floatx4){0.f, 0.f, 0.f, 0.f};
    }
    #pragma unroll
    for (int cg = 0; cg < 4; cg++) acc12[cg] = (floatx4){0.f, 0.f, 0.f, 0.f};
    accl12 = (floatx4){0.f, 0.f, 0.f, 0.f};

    union { u32 w[4]; short8 s; } ones;
    ones.w[0] = 0x3F803F80u; ones.w[1] = 0x3F803F80u;
    ones.w[2] = 0x3F803F80u; ones.w[3] = 0x3F803F80u;

    #define KLOAD(c, D00, D01, D10, D11) do {                                    \
        const u16* a0_ = kfr0 + (size_t)(rbase + (c) * 32 + l15) * CID + quad * 8;\
        const u16* a1_ = a0_ + (size_t)16 * CID;                                 \
        D00 = *(const short8*)a0_;  D01 = *(const short8*)(a0_ + 32);            \
        D10 = *(const short8*)a1_;  D11 = *(const short8*)(a1_ + 32);            \
    } while (0)

    #define KLOADTAIL(D00, D01) do {                                             \
        int g_ = rbase + 192 + l15;                                              \
        g_ = g_ < (TP * HWP - 1) ? g_ : (TP * HWP - 1);                          \
        const u16* a0_ = kfr0 + (size_t)g_ * CID + quad * 8;                     \
        D00 = *(const short8*)a0_;  D01 = *(const short8*)(a0_ + 32);            \
    } while (0)

    #define VLOAD(c, D0, D1, D2, D3) do {                                        \
        const u16* v_ = vfr + l15 * VSLOT + (c) * 32 + quad * 8;                 \
        D0 = *(const short8*)v_;                                                 \
        D1 = *(const short8*)(v_ + 16 * VSLOT);                                  \
        D2 = *(const short8*)(v_ + 32 * VSLOT);                                  \
        D3 = *(const short8*)(v_ + 48 * VSLOT);                                  \
    } while (0)

    #define CHUNK_ONE(Q0, Q1, ACC, ACCL, K00, K01, K10, K11, V0, V1, V2, V3) do {\
        floatx4 sc0 = (floatx4){0.f, 0.f, 0.f, 0.f};                             \
        sc0 = __builtin_amdgcn_mfma_f32_16x16x32_bf16(K00, Q0, sc0, 0, 0, 0);    \
        sc0 = __builtin_amdgcn_mfma_f32_16x16x32_bf16(K01, Q1, sc0, 0, 0, 0);    \
        floatx4 sc1 = (floatx4){0.f, 0.f, 0.f, 0.f};                             \
        sc1 = __builtin_amdgcn_mfma_f32_16x16x32_bf16(K10, Q0, sc1, 0, 0, 0);    \
        sc1 = __builtin_amdgcn_mfma_f32_16x16x32_bf16(K11, Q1, sc1, 0, 0, 0);    \
        union { u32 w[4]; short8 s; } pf;                                        \
        pf.w[0] = packtrunc(fexp2(sc0[0]), fexp2(sc0[1]));                       \
        pf.w[1] = packtrunc(fexp2(sc0[2]), fexp2(sc0[3]));                       \
        pf.w[2] = packtrunc(fexp2(sc1[0]), fexp2(sc1[1]));                       \
        pf.w[3] = packtrunc(fexp2(sc1[2]), fexp2(sc1[3]));                       \
        ACC[0] = __builtin_amdgcn_mfma_f32_16x16x32_bf16(pf.s, V0, ACC[0], 0, 0, 0); \
        ACC[1] = __builtin_amdgcn_mfma_f32_16x16x32_bf16(pf.s, V1, ACC[1], 0, 0, 0); \
        ACC[2] = __builtin_amdgcn_mfma_f32_16x16x32_bf16(pf.s, V2, ACC[2], 0, 0, 0); \
        ACC[3] = __builtin_amdgcn_mfma_f32_16x16x32_bf16(pf.s, V3, ACC[3], 0, 0, 0); \
        ACCL   = __builtin_amdgcn_mfma_f32_16x16x32_bf16(pf.s, ones.s, ACCL, 0, 0, 0); \
    } while (0)

    #define TAIL_ONE(Q0, Q1, ACC, ACCL, K00, K01, V0, V1, V2, V3) do {           \
        floatx4 sc0 = (floatx4){0.f, 0.f, 0.f, 0.f};                             \
        sc0 = __builtin_amdgcn_mfma_f32_16x16x32_bf16(K00, Q0, sc0, 0, 0, 0);    \
        sc0 = __builtin_amdgcn_mfma_f32_16x16x32_bf16(K01, Q1, sc0, 0, 0, 0);    \
        union { u32 w[4]; short8 s; } pf;                                        \
        pf.w[0] = packtrunc(fexp2(sc0[0]) * tmask, fexp2(sc0[1]) * tmask);       \
        pf.w[1] = packtrunc(fexp2(sc0[2]) * tmask, fexp2(sc0[3]) * tmask);       \
        pf.w[2] = 0u;                                                            \
        pf.w[3] = 0u;                                                            \
        ACC[0] = __builtin_amdgcn_mfma_f32_16x16x32_bf16(pf.s, V0, ACC[0], 0, 0, 0); \
        ACC[1] = __builtin_amdgcn_mfma_f32_16x16x32_bf16(pf.s, V1, ACC[1], 0, 0, 0); \
        ACC[2] = __builtin_amdgcn_mfma_f32_16x16x32_bf16(pf.s, V2, ACC[2], 0, 0, 0); \
        ACC[3] = __builtin_amdgcn_mfma_f32_16x16x32_bf16(pf.s, V3, ACC[3], 0, 0, 0); \
        ACCL   = __builtin_amdgcn_mfma_f32_16x16x32_bf16(pf.s, ones.s, ACCL, 0, 0, 0); \
    } while (0)

    #define CHUNK_FULL(K00, K01, K10, K11, V0, V1, V2, V3) do {                  \
        _Pragma("unroll")                                                        \
        for (int j = 0; j < 3; j++)                                              \
            CHUNK_ONE(qf[j][0], qf[j][1], acc[j], accl[j],                       \
                      K00, K01, K10, K11, V0, V1, V2, V3);                       \
        if (do12)                                                                \
            CHUNK_ONE(qf12[0], qf12[1], acc12, accl12,                           \
                      K00, K01, K10, K11, V0, V1, V2, V3);                       \
    } while (0)

    #define CHUNK_TAIL(K00, K01, V0, V1, V2, V3) do {                            \
        _Pragma("unroll")                                                        \
        for (int j = 0; j < 3; j++)                                              \
            TAIL_ONE(qf[j][0], qf[j][1], acc[j], accl[j],                        \
                     K00, K01, V0, V1, V2, V3);                                  \
        if (do12)                                                                \
            TAIL_ONE(qf12[0], qf12[1], acc12, accl12,                            \
                     K00, K01, V0, V1, V2, V3);                                  \
    } while (0)

    for (int f = 0; f < KWIN; f++) {
        int rbase = (t + f) * HWP;
        const u16* vfr = vslab + (size_t)(t + f) * (64 * VSLOT);
        bool do12 = ((f & 3) == wave);   // frame-distributed tile 12

        short8 ka00, ka01, ka10, ka11, va0, va1, va2, va3;
        short8 kb00, kb01, kb10, kb11, vb0, vb1, vb2, vb3;
        short8 kc00, kc01, kc10, kc11, vc0, vc1, vc2, vc3;

        // Depth-2 pipeline: 3 chunk-loads in flight before first compute.
        KLOAD(0, ka00, ka01, ka10, ka11);  VLOAD(0, va0, va1, va2, va3);
        KLOAD(1, kb00, kb01, kb10, kb11);  VLOAD(1, vb0, vb1, vb2, vb3);
        KLOAD(2, kc00, kc01, kc10, kc11);  VLOAD(2, vc0, vc1, vc2, vc3);
        CHUNK_FULL(ka00, ka01, ka10, ka11, va0, va1, va2, va3);      // c=0
        KLOAD(3, ka00, ka01, ka10, ka11);  VLOAD(3, va0, va1, va2, va3);
        CHUNK_FULL(kb00, kb01, kb10, kb11, vb0, vb1, vb2, vb3);      // c=1
        KLOAD(4, kb00, kb01, kb10, kb11);  VLOAD(4, vb0, vb1, vb2, vb3);
        CHUNK_FULL(kc00, kc01, kc10, kc11, vc0, vc1, vc2, vc3);      // c=2
        KLOAD(5, kc00, kc01, kc10, kc11);  VLOAD(5, vc0, vc1, vc2, vc3);
        CHUNK_FULL(ka00, ka01, ka10, ka11, va0, va1, va2, va3);      // c=3
        KLOADTAIL(ka00, ka01);             VLOAD(6, va0, va1, va2, va3);
        CHUNK_FULL(kb00, kb01, kb10, kb11, vb0, vb1, vb2, vb3);      // c=4
        CHUNK_FULL(kc00, kc01, kc10, kc11, vc0, vc1, vc2, vc3);      // c=5
        CHUNK_TAIL(ka00, ka01, va0, va1, va2, va3);                  // keys 192..195
    }

    #undef KLOAD
    #undef KLOADTAIL
    #undef VLOAD
    #undef CHUNK_ONE
    #undef TAIL_ONE
    #undef CHUNK_FULL
    #undef CHUNK_TAIL

    // Epilogue: main tiles normalized into eT (rows 0..191); tile-12 raw
    // partials into eT12/ls12; combine + normalize at store.
    #pragma unroll
    for (int j = 0; j < 3; j++) {
        int tg = wave + 4 * j;
        float il[4];
        #pragma unroll
        for (int rr = 0; rr < 4; rr++) il[rr] = 1.0f / accl[j][rr];
        #pragma unroll
        for (int cg = 0; cg < 4; cg++) {
            #pragma unroll
            for (int rr = 0; rr < 4; rr++) {
                int p = tg * 16 + quad * 4 + rr;     // always < 192
                eT[p * 66 + cg * 16 + l15] = acc[j][cg][rr] * il[rr];
            }
        }
    }
    if (quad == 0) {
        #pragma unroll
        for (int rr = 0; rr < 4; rr++) {
            #pragma unroll
            for (int cg = 0; cg < 4; cg++)
                eT12[wave][rr][cg * 16 + l15] = acc12[cg][rr];
            if (l15 == 0) ls12[wave][rr] = accl12[rr];
        }
    }
    __syncthreads();

    if (tid < HWP) {
        size_t base = ((size_t)(b * CC + n * CID) * TT + t) * HWP + tid;
        if (tid < 192) {
            for (int ci = 0; ci < 64; ci++) {
                size_t a = base + (size_t)ci * (TT * HWP);
                zout[a] = eT[tid * 66 + ci] + x[a];
            }
        } else {
            int rr = tid - 192;
            float l = ls12[0][rr] + ls12[1][rr] + ls12[2][rr] + ls12[3][rr];
            float il = 1.0f / l;
            for (int ci = 0; ci < 64; ci++) {
                size_t a = base + (size_t)ci * (TT * HWP);
                float v = (eT12[0][rr][ci] + eT12[1][rr][ci]
                         + eT12[2][rr][ci] + eT12[3][rr][ci]) * il;
                zout[a] = v + x[a];
            }
        }
    }
}

// ---------------------------------------------------------------------------
extern "C" void kernel_launch(void* const* d_in, const int* in_sizes, int n_in,
                              void* d_out, int out_size, void* d_ws, size_t ws_size,
                              hipStream_t stream) {
    const float* x  = (const float*)d_in[0];
    const float* Wq = (const float*)d_in[1];
    const float* bq = (const float*)d_in[2];
    const float* Wk = (const float*)d_in[3];
    const float* bk = (const float*)d_in[4];
    const float* Wv = (const float*)d_in[5];
    const float* bv = (const float*)d_in[6];
    float* z = (float*)d_out;

    // ws (bf16): Q, K, Vtp, W (~48.8 MB, proven). d_out scratch: xt only.
    const size_t qElems   = (size_t)BB * NH * TT * HWP * CID;   // 6,422,528
    const size_t kElems   = (size_t)BB * NH * TP * HWP * CID;   // 8,028,160
    const size_t vtpElems = (size_t)BB * NH * TP * 64 * VSLOT;  // 9,175,040

    u16* Qw  = (u16*)d_ws;
    u16* Kw  = Qw + qElems;
    u16* Vtp = Kw + kElems;
    u16* Wb  = Vtp + vtpElems;
    u16* Xt  = (u16*)d_out;

    {
        const int wtot = NTOT * CC / 2;
        const int kper = 2 * NH * 8 * HWP * 32;
        const int vper = 2 * NH * 8 * 64 * (VSLOT / 2);
        const int prepBlocks = (wtot + kper + vper + 255) / 256;   // 8256
        prep_transpose<<<BB * TT * 8 + prepBlocks, 256, 0, stream>>>(
            x, Xt, Wq, Wk, Wv, Wb, bk, bv, Kw, Vtp);
    }
    // 98 m-tiles x 6 n-tiles, 512 threads; gload_lds staging, fused V write.
    proj_gemm2<<<98 * 6, 512, 0, stream>>>(Xt, Wb, bq, bk, bv, Qw, Kw, Vtp);
    // 16 slabs * 32 t, 4 waves/block, XCD-swizzled; 512 blocks.
    attn_mfma4<<<512, 256, 0, stream>>>(x, Qw, Kw, Vtp, z);
}

// Round 18
// 213.044 us; speedup vs baseline: 1.1461x; 1.1253x over previous
//
#include <hip/hip_runtime.h>
#include <hip/hip_bf16.h>
#include <stdint.h>
#include <cstddef>

// Problem constants
#define BB  2
#define CC  512
#define TT  32
#define HWP 196   // H*W = 14*14
#define NH  8
#define KWIN 9
#define CID 64    // C / N
#define PPAD 4    // (K-1)/2
#define TP  40    // T + 2P
#define MTOT 12544  // BB*TT*HWP
#define NTOT 1536   // 3*CC (Q|K|V output channels)
#define VSLOT 224   // padded per-frame key slots (7*32)
#define LOG2E 1.44269504f

typedef unsigned short u16;
typedef unsigned int   u32;
typedef __attribute__((ext_vector_type(8))) short short8;
typedef __attribute__((ext_vector_type(4))) float floatx4;

__device__ __forceinline__ u16 f2bf(float f) {
    u32 u = __float_as_uint(f);
    u32 r = (u + 0x7fffu + ((u >> 16) & 1u)) >> 16;
    return (u16)r;
}
__device__ __forceinline__ u32 pack2bf(float a, float b) {
    return (u32)f2bf(a) | ((u32)f2bf(b) << 16);
}
// Truncating pack: [hi16(b) : hi16(a)] in one v_perm_b32.
__device__ __forceinline__ u32 packtrunc(float a, float b) {
    return __builtin_amdgcn_perm(__float_as_uint(b), __float_as_uint(a), 0x07060302u);
}
// Raw hardware exp2 (v_exp_f32, 1 ulp).
__device__ __forceinline__ float fexp2(float x) {
    return __builtin_amdgcn_exp2f(x);
}
// Async global->LDS, 16 B per lane. LDS dest is WAVE-UNIFORM base; HW writes
// lane l at base + l*16. Global src is per-lane.
__device__ __forceinline__ void gload16(const u16* g, u16* l) {
    __builtin_amdgcn_global_load_lds(
        (const __attribute__((address_space(1))) u32*)g,
        (__attribute__((address_space(3))) u32*)l, 16, 0, 0);
}

// ---------------------------------------------------------------------------
// Prep (fused): transpose_x (blocks 0..511) + W-concat/pad-fill (rest).
// Vectorized transpose branch (float4 in, uint4 out).
// ---------------------------------------------------------------------------
__global__ __launch_bounds__(256) void prep_transpose(
    const float* __restrict__ x, u16* __restrict__ xt,
    const float* __restrict__ Wq, const float* __restrict__ Wk,
    const float* __restrict__ Wv, u16* __restrict__ Wbf,
    const float* __restrict__ bk, const float* __restrict__ bv,
    u16* __restrict__ Kout, u16* __restrict__ Vtp)
{
    __shared__ float T[64 * 197];
    int bxg = blockIdx.x;
    int tid = threadIdx.x;

    if (bxg < BB * TT * 8) {
        // --- transpose x[b][c][t][p] fp32 -> xt[(b*T+t)*HW+p][c] bf16 ---
        int bx = bxg;
        int ct = bx & 7; bx >>= 3;
        int t = bx & 31;
        int b = bx >> 5;
        const float* src = x + ((size_t)(b * CC + ct * 64) * TT + t) * HWP;
        for (int i = tid; i < 64 * 49; i += 256) {
            int c = i / 49;
            int p4 = i - c * 49;
            float4 v = *(const float4*)(src + (size_t)c * (TT * HWP) + p4 * 4);
            float* Tp = &T[c * 197 + p4 * 4];
            Tp[0] = v.x; Tp[1] = v.y; Tp[2] = v.z; Tp[3] = v.w;
        }
        __syncthreads();
        u16* dst = xt + (size_t)((b * TT + t) * HWP) * CC + ct * 64;
        for (int i = tid; i < HWP * 8; i += 256) {
            int p = i >> 3;
            int c0 = (i & 7) * 8;
            u32 w[4];
            #pragma unroll
            for (int k = 0; k < 4; k++)
                w[k] = pack2bf(T[(c0 + 2 * k) * 197 + p],
                               T[(c0 + 2 * k + 1) * 197 + p]);
            *(uint4*)(dst + (size_t)p * CC + c0) = *(uint4*)w;
        }
        return;
    }

    // --- W concat fp32->bf16 + pad-frame fill for K and Vtp ---
    int id = (bxg - BB * TT * 8) * 256 + tid;
    const int wtot = NTOT * CC / 2;                // 393,216 u32 (W)
    const int kper = 2 * NH * 8 * HWP * 32;        // 802,816 u32 (K pads)
    const int vper = 2 * NH * 8 * 64 * (VSLOT/2);  // 917,504 u32 (Vtp pads)
    if (id < wtot) {
        int c2 = id & 255;
        int oc = id >> 8;
        int kind = oc >> 9;
        int idx = oc & 511;
        const float* src = (kind == 0 ? Wq : (kind == 1 ? Wk : Wv)) + (size_t)idx * CC + c2 * 2;
        ((u32*)Wbf)[id] = pack2bf(src[0], src[1]);
    } else if (id < wtot + kper) {
        int i = id - wtot;
        int ci2 = i & 31; i >>= 5;
        int p = i % HWP;  i /= HWP;
        int fr = i & 7;   i >>= 3;
        int head = i & 7;
        int b = i >> 3;
        int tp = fr < 4 ? fr : fr + 32;
        const float* bias = bk + head * CID + ci2 * 2;
        size_t addr = (((size_t)(b * NH + head) * TP + tp) * HWP + p) * 32 + ci2;
        ((u32*)Kout)[addr] = pack2bf(bias[0], bias[1]);
    } else if (id < wtot + kper + vper) {
        int i = id - wtot - kper;
        int s2 = i % (VSLOT/2); i /= (VSLOT/2);
        int ci = i & 63; i >>= 6;
        int fr = i & 7;  i >>= 3;
        int head = i & 7;
        int b = i >> 3;
        int tp = fr < 4 ? fr : fr + 32;
        float bias = bv[head * CID + ci];
        size_t addr = (((size_t)(b * NH + head) * TP + tp) * 64 + ci) * (VSLOT/2) + s2;
        ((u32*)Vtp)[addr] = pack2bf(bias, bias);   // whole row = bias[ci]
    }
}

// ---------------------------------------------------------------------------
// MFMA projection GEMM v4 (R14/R15/R17-verified, UNCHANGED): gload_lds
// staging + fused V epilogue writing Vtp directly via inverse slot perm.
// ---------------------------------------------------------------------------
__global__ __launch_bounds__(512) void proj_gemm2(
    const u16* __restrict__ xt, const u16* __restrict__ Wbf,
    const float* __restrict__ bq, const float* __restrict__ bk,
    const float* __restrict__ bv,
    u16* __restrict__ Qout, u16* __restrict__ Kout, u16* __restrict__ Vtp)
{
    __shared__ u16 sA[128 * 64];   // 16 KB linear (swizzled content)
    __shared__ u16 sB[256 * 64];   // 32 KB

    int bx = blockIdx.x;
    int nb = bx % 6;
    int mt = bx / 6;
    int tid = threadIdx.x;
    int wave = tid >> 6, lane = tid & 63, quad = lane >> 4, l15 = lane & 15;
    int wm = wave >> 2, wn = wave & 3;
    int mbase = mt * 128 + wm * 64;
    int nbase = nb * 256 + wn * 64;

    int lr = lane >> 3;                        // row within 8-row group
    int sw = ((lane & 7) * 8) ^ (lr << 3);     // swizzled u16 col (source side)

    floatx4 acc[4][4];
    #pragma unroll
    for (int ms = 0; ms < 4; ms++)
        #pragma unroll
        for (int ns = 0; ns < 4; ns++)
            acc[ms][ns] = (floatx4){0.f, 0.f, 0.f, 0.f};

    const u16* abase = xt + (size_t)(mt * 128) * CC;
    const u16* bbase = Wbf + (size_t)(nb * 256) * CC;

    for (int kc = 0; kc < 8; kc++) {
        __syncthreads();   // previous tile's LDS reads complete
        #pragma unroll
        for (int i = 0; i < 2; i++) {
            int rbase = wave * 16 + i * 8;
            gload16(abase + (size_t)(rbase + lr) * CC + kc * 64 + sw,
                    &sA[rbase * 64]);
        }
        #pragma unroll
        for (int i = 0; i < 4; i++) {
            int rbase = wave * 32 + i * 8;
            gload16(bbase + (size_t)(rbase + lr) * CC + kc * 64 + sw,
                    &sB[rbase * 64]);
        }
        __syncthreads();   // compiler drains vmcnt before the barrier

        #pragma unroll
        for (int kk = 0; kk < 2; kk++) {
            int swr = (kk * 32 + quad * 8) ^ ((l15 & 7) << 3);   // read swizzle
            short8 af[4], bf[4];
            #pragma unroll
            for (int ms = 0; ms < 4; ms++)
                af[ms] = *(const short8*)&sA[(wm * 64 + ms * 16 + l15) * 64 + swr];
            #pragma unroll
            for (int ns = 0; ns < 4; ns++)
                bf[ns] = *(const short8*)&sB[(wn * 64 + ns * 16 + l15) * 64 + swr];
            #pragma unroll
            for (int ms = 0; ms < 4; ms++)
                #pragma unroll
                for (int ns = 0; ns < 4; ns++)
                    acc[ms][ns] = __builtin_amdgcn_mfma_f32_16x16x32_bf16(
                        af[ms], bf[ns], acc[ms][ns], 0, 0, 0);
        }
    }

    float biasv[4];
    #pragma unroll
    for (int ns = 0; ns < 4; ns++) {
        int n = nbase + ns * 16 + l15;
        int kind = n >> 9;
        int idx = n & 511;
        const float* bpb = kind == 0 ? bq : (kind == 1 ? bk : bv);
        biasv[ns] = bpb[idx];
    }

    #pragma unroll
    for (int ms = 0; ms < 4; ms++) {
        #pragma unroll
        for (int r = 0; r < 4; r++) {
            int m = mbase + ms * 16 + quad * 4 + r;
            int b = m / (TT * HWP);
            int rem = m - b * (TT * HWP);
            int t = rem / HWP;
            int p = rem - t * HWP;
            // inverse slot permutation for the fused Vtp write
            int slot_p = (p & ~31) | (p & 3) | (((p >> 4) & 1) << 2)
                       | (((p >> 2) & 1) << 3) | (((p >> 3) & 1) << 4);
            #pragma unroll
            for (int ns = 0; ns < 4; ns++) {
                int n = nbase + ns * 16 + l15;
                int kind = n >> 9;          // uniform across block (kind = nb>>1)
                int idx = n & 511;
                int head = idx >> 6;
                int ci = idx & 63;
                float val = acc[ms][ns][r] + biasv[ns];
                if (kind == 0) {
                    Qout[(((size_t)(b * NH + head) * TT + t) * HWP + p) * CID + ci]
                        = f2bf(val * LOG2E);
                } else if (kind == 1) {
                    Kout[(((size_t)(b * NH + head) * TP + (t + PPAD)) * HWP + p) * CID + ci]
                        = f2bf(val);
                } else {
                    Vtp[(((size_t)(b * NH + head) * TP + (t + PPAD)) * 64 + ci) * VSLOT + slot_p]
                        = f2bf(val);
                }
            }
        }
    }
}

// ---------------------------------------------------------------------------
// MFMA flash attention v14: LDS-shared K/V via gload_lds.
// THEORY (fits all R0-R17 data): attn was L1-return-BW bound — all 4 waves
// of a block loaded the SAME K/V bytes (64 KB L1 traffic per CU per
// chunk-step at ~64 B/cy = the measured ~1040-cy budget). Now K (208 rows,
// swizzled per rule-21 like proj) and V (linear [64][224], bank-balanced
// for b128 reads as-is) are staged ONCE per block per frame with
// global_load_lds; waves read fragments from LDS (128 B/cy, ~2x L1 BW,
// 4x less redundant traffic). Tile structure = R15's dead-tile-free
// (3 main tiles/wave + frame-distributed tile 12). Epilogue unchanged,
// LDS unioned with staging buffers (55,296 B, 2 blocks/CU as before).
// ---------------------------------------------------------------------------
__global__ __launch_bounds__(256, 1) void attn_mfma4(
    const float* __restrict__ x,
    const u16* __restrict__ Qb, const u16* __restrict__ Kb,
    const u16* __restrict__ Vtp, float* __restrict__ zout)
{
    __shared__ union {
        struct { u16 K[26 * 512]; u16 V[28 * 512]; } s;   // 26,624+28,672 = 55,296 B
        struct { float eT[192 * 66]; float eT12[4][4][66]; float ls12[4][4]; } e;
    } u;                                                   // union: 55,296 B

    int i = blockIdx.x;
    int xcd = i & 7;
    int r = i >> 3;                        // 0..63
    int slab = ((r >= 32) ? 8 : 0) | xcd;  // slab pinned to one XCD
    int t = r & 31;
    int b = slab >> 3, n = slab & 7;

    int tid = threadIdx.x;
    int wave = tid >> 6;
    int lane = tid & 63;
    int quad = lane >> 4, l15 = lane & 15;
    int lr = lane >> 3;                          // staging row-in-group
    int ksw = ((lane & 7) * 8) ^ (lr << 3);      // K source swizzle (u16)

    const u16* kfr0 = Kb + (size_t)slab * (TP * HWP) * CID;
    const u16* vslab = Vtp + (size_t)slab * (TP * 64 * VSLOT);
    const float tmask = (quad == 0) ? 1.0f : 0.0f;

    // Q B-frags: main tiles tg = wave + 4*j (j=0..2, rows <= 191, no clamp)
    short8 qf[3][2];
    #pragma unroll
    for (int j = 0; j < 3; j++) {
        int qrow = (wave + 4 * j) * 16 + l15;
        const u16* qp = Qb + ((size_t)(slab * TT + t) * HWP + qrow) * CID;
        qf[j][0] = *(const short8*)(qp + quad * 8);
        qf[j][1] = *(const short8*)(qp + 32 + quad * 8);
    }
    // Tile 12 (rows 192..195 valid; clamp dups row 195 for l15 > 3)
    short8 qf12[2];
    {
        int qrow = 192 + l15;
        qrow = qrow < HWP ? qrow : (HWP - 1);
        const u16* qp = Qb + ((size_t)(slab * TT + t) * HWP + qrow) * CID;
        qf12[0] = *(const short8*)(qp + quad * 8);
        qf12[1] = *(const short8*)(qp + 32 + quad * 8);
    }

    floatx4 acc[3][4];
    floatx4 accl[3];
    floatx4 acc12[4];
    floatx4 accl12;
    #pragma unroll
    for (int j = 0; j < 3; j++) {
        #pragma unroll
        for (int cg = 0; cg < 4; cg++) acc[j][cg] = (floatx4){0.f, 0.f, 0.f, 0.f};
        accl[j] = (floatx4){0.f, 0.f, 0.f, 0.f};
    }
    #pragma unroll
    for (int cg = 0; cg < 4; cg++) acc12[cg] = (floatx4){0.f, 0.f, 0.f, 0.f};
    accl12 = (floatx4){0.f, 0.f, 0.f, 0.f};

    union { u32 w[4]; short8 s; } ones;
    ones.w[0] = 0x3F803F80u; ones.w[1] = 0x3F803F80u;
    ones.w[2] = 0x3F803F80u; ones.w[3] = 0x3F803F80u;

    // LDS K read: content is swizzled LDS[row][c] = G[row][c ^ ((row&7)<<3)],
    // so reading col c applies the same XOR (bijective within the 64-u16 row).
    #define KLOAD_L(c, D00, D01, D10, D11) do {                                  \
        int r0_ = (c) * 32 + l15;                                                \
        int sx_ = (l15 & 7) << 3;                                                \
        const u16* a0_ = &u.s.K[r0_ * 64];                                       \
        const u16* a1_ = &u.s.K[(r0_ + 16) * 64];                                \
        D00 = *(const short8*)(a0_ + ((quad * 8) ^ sx_));                        \
        D01 = *(const short8*)(a0_ + ((32 + quad * 8) ^ sx_));                   \
        D10 = *(const short8*)(a1_ + ((quad * 8) ^ sx_));                        \
        D11 = *(const short8*)(a1_ + ((32 + quad * 8) ^ sx_));                   \
    } while (0)

    // Tail: rows 192..207 are all staged (26 chunks x 8 rows = 208).
    #define KLOADTAIL_L(D00, D01) do {                                           \
        int r0_ = 192 + l15;                                                     \
        int sx_ = (l15 & 7) << 3;                                                \
        const u16* a0_ = &u.s.K[r0_ * 64];                                       \
        D00 = *(const short8*)(a0_ + ((quad * 8) ^ sx_));                        \
        D01 = *(const short8*)(a0_ + ((32 + quad * 8) ^ sx_));                   \
    } while (0)

    // LDS V read: linear [64][VSLOT]; bank-balanced for b128 as-is.
    #define VLOAD_L(c, D0, D1, D2, D3) do {                                      \
        const u16* v_ = &u.s.V[l15 * VSLOT + (c) * 32 + quad * 8];               \
        D0 = *(const short8*)(v_);                                               \
        D1 = *(const short8*)(v_ + 16 * VSLOT);                                  \
        D2 = *(const short8*)(v_ + 32 * VSLOT);                                  \
        D3 = *(const short8*)(v_ + 48 * VSLOT);                                  \
    } while (0)

    #define CHUNK_ONE(Q0, Q1, ACC, ACCL, K00, K01, K10, K11, V0, V1, V2, V3) do {\
        floatx4 sc0 = (floatx4){0.f, 0.f, 0.f, 0.f};                             \
        sc0 = __builtin_amdgcn_mfma_f32_16x16x32_bf16(K00, Q0, sc0, 0, 0, 0);    \
        sc0 = __builtin_amdgcn_mfma_f32_16x16x32_bf16(K01, Q1, sc0, 0, 0, 0);    \
        floatx4 sc1 = (floatx4){0.f, 0.f, 0.f, 0.f};                             \
        sc1 = __builtin_amdgcn_mfma_f32_16x16x32_bf16(K10, Q0, sc1, 0, 0, 0);    \
        sc1 = __builtin_amdgcn_mfma_f32_16x16x32_bf16(K11, Q1, sc1, 0, 0, 0);    \
        union { u32 w[4]; short8 s; } pf;                                        \
        pf.w[0] = packtrunc(fexp2(sc0[0]), fexp2(sc0[1]));                       \
        pf.w[1] = packtrunc(fexp2(sc0[2]), fexp2(sc0[3]));                       \
        pf.w[2] = packtrunc(fexp2(sc1[0]), fexp2(sc1[1]));                       \
        pf.w[3] = packtrunc(fexp2(sc1[2]), fexp2(sc1[3]));                       \
        ACC[0] = __builtin_amdgcn_mfma_f32_16x16x32_bf16(pf.s, V0, ACC[0], 0, 0, 0); \
        ACC[1] = __builtin_amdgcn_mfma_f32_16x16x32_bf16(pf.s, V1, ACC[1], 0, 0, 0); \
        ACC[2] = __builtin_amdgcn_mfma_f32_16x16x32_bf16(pf.s, V2, ACC[2], 0, 0, 0); \
        ACC[3] = __builtin_amdgcn_mfma_f32_16x16x32_bf16(pf.s, V3, ACC[3], 0, 0, 0); \
        ACCL   = __builtin_amdgcn_mfma_f32_16x16x32_bf16(pf.s, ones.s, ACCL, 0, 0, 0); \
    } while (0)

    #define TAIL_ONE(Q0, Q1, ACC, ACCL, K00, K01, V0, V1, V2, V3) do {           \
        floatx4 sc0 = (floatx4){0.f, 0.f, 0.f, 0.f};                             \
        sc0 = __builtin_amdgcn_mfma_f32_16x16x32_bf16(K00, Q0, sc0, 0, 0, 0);    \
        sc0 = __builtin_amdgcn_mfma_f32_16x16x32_bf16(K01, Q1, sc0, 0, 0, 0);    \
        union { u32 w[4]; short8 s; } pf;                                        \
        pf.w[0] = packtrunc(fexp2(sc0[0]) * tmask, fexp2(sc0[1]) * tmask);       \
        pf.w[1] = packtrunc(fexp2(sc0[2]) * tmask, fexp2(sc0[3]) * tmask);       \
        pf.w[2] = 0u;                                                            \
        pf.w[3] = 0u;                                                            \
        ACC[0] = __builtin_amdgcn_mfma_f32_16x16x32_bf16(pf.s, V0, ACC[0], 0, 0, 0); \
        ACC[1] = __builtin_amdgcn_mfma_f32_16x16x32_bf16(pf.s, V1, ACC[1], 0, 0, 0); \
        ACC[2] = __builtin_amdgcn_mfma_f32_16x16x32_bf16(pf.s, V2, ACC[2], 0, 0, 0); \
        ACC[3] = __builtin_amdgcn_mfma_f32_16x16x32_bf16(pf.s, V3, ACC[3], 0, 0, 0); \
        ACCL   = __builtin_amdgcn_mfma_f32_16x16x32_bf16(pf.s, ones.s, ACCL, 0, 0, 0); \
    } while (0)

    #define CHUNK_FULL(K00, K01, K10, K11, V0, V1, V2, V3) do {                  \
        _Pragma("unroll")                                                        \
        for (int j = 0; j < 3; j++)                                              \
            CHUNK_ONE(qf[j][0], qf[j][1], acc[j], accl[j],                       \
                      K00, K01, K10, K11, V0, V1, V2, V3);                       \
        if (do12)                                                                \
            CHUNK_ONE(qf12[0], qf12[1], acc12, accl12,                           \
                      K00, K01, K10, K11, V0, V1, V2, V3);                       \
    } while (0)

    #define CHUNK_TAIL(K00, K01, V0, V1, V2, V3) do {                            \
        _Pragma("unroll")                                                        \
        for (int j = 0; j < 3; j++)                                              \
            TAIL_ONE(qf[j][0], qf[j][1], acc[j], accl[j],                        \
                     K00, K01, V0, V1, V2, V3);                                  \
        if (do12)                                                                \
            TAIL_ONE(qf12[0], qf12[1], acc12, accl12,                            \
                     K00, K01, V0, V1, V2, V3);                                  \
    } while (0)

    for (int f = 0; f < KWIN; f++) {
        int rbase = (t + f) * HWP;
        const u16* kfr = kfr0 + (size_t)rbase * CID;
        const u16* vfr = vslab + (size_t)(t + f) * (64 * VSLOT);
        bool do12 = ((f & 3) == wave);   // frame-distributed tile 12

        __syncthreads();   // previous frame's LDS reads complete
        // Stage K (26 chunks: rows 0..207, swizzled source) and V (28 chunks:
        // [64][224] linear copy). 54 chunks over 4 waves, wave-uniform split.
        #pragma unroll
        for (int it = 0; it < 14; it++) {
            int idx = it * 4 + wave;
            if (idx < 26) {
                gload16(kfr + (size_t)(idx * 8 + lr) * CID + ksw,
                        &u.s.K[idx * 512]);
            } else if (idx < 54) {
                int j2 = idx - 26;
                gload16(vfr + j2 * 512 + lane * 8, &u.s.V[j2 * 512]);
            }
        }
        __syncthreads();   // vmcnt drained by compiler before barrier

        // 6 full 32-key chunks + tail, fragments read just-in-time from LDS.
        #pragma unroll
        for (int c = 0; c < 6; c++) {
            short8 k00, k01, k10, k11, v0, v1, v2, v3;
            KLOAD_L(c, k00, k01, k10, k11);
            VLOAD_L(c, v0, v1, v2, v3);
            CHUNK_FULL(k00, k01, k10, k11, v0, v1, v2, v3);
        }
        {
            short8 k00, k01, v0, v1, v2, v3;
            KLOADTAIL_L(k00, k01);
            VLOAD_L(6, v0, v1, v2, v3);
            CHUNK_TAIL(k00, k01, v0, v1, v2, v3);   // keys 192..195
        }
    }

    #undef KLOAD_L
    #undef KLOADTAIL_L
    #undef VLOAD_L
    #undef CHUNK_ONE
    #undef TAIL_ONE
    #undef CHUNK_FULL
    #undef CHUNK_TAIL

    __syncthreads();   // all K/V LDS reads done before aliasing with eT

    // Epilogue: main tiles normalized into eT (rows 0..191); tile-12 raw
    // partials into eT12/ls12; combine + normalize at store.
    #pragma unroll
    for (int j = 0; j < 3; j++) {
        int tg = wave + 4 * j;
        float il[4];
        #pragma unroll
        for (int rr = 0; rr < 4; rr++) il[rr] = 1.0f / accl[j][rr];
        #pragma unroll
        for (int cg = 0; cg < 4; cg++) {
            #pragma unroll
            for (int rr = 0; rr < 4; rr++) {
                int p = tg * 16 + quad * 4 + rr;     // always < 192
                u.e.eT[p * 66 + cg * 16 + l15] = acc[j][cg][rr] * il[rr];
            }
        }
    }
    if (quad == 0) {
        #pragma unroll
        for (int rr = 0; rr < 4; rr++) {
            #pragma unroll
            for (int cg = 0; cg < 4; cg++)
                u.e.eT12[wave][rr][cg * 16 + l15] = acc12[cg][rr];
            if (l15 == 0) u.e.ls12[wave][rr] = accl12[rr];
        }
    }
    __syncthreads();

    if (tid < HWP) {
        size_t base = ((size_t)(b * CC + n * CID) * TT + t) * HWP + tid;
        if (tid < 192) {
            for (int ci = 0; ci < 64; ci++) {
                size_t a = base + (size_t)ci * (TT * HWP);
                zout[a] = u.e.eT[tid * 66 + ci] + x[a];
            }
        } else {
            int rr = tid - 192;
            float l = u.e.ls12[0][rr] + u.e.ls12[1][rr]
                    + u.e.ls12[2][rr] + u.e.ls12[3][rr];
            float il = 1.0f / l;
            for (int ci = 0; ci < 64; ci++) {
                size_t a = base + (size_t)ci * (TT * HWP);
                float v = (u.e.eT12[0][rr][ci] + u.e.eT12[1][rr][ci]
                         + u.e.eT12[2][rr][ci] + u.e.eT12[3][rr][ci]) * il;
                zout[a] = v + x[a];
            }
        }
    }
}

// ---------------------------------------------------------------------------
extern "C" void kernel_launch(void* const* d_in, const int* in_sizes, int n_in,
                              void* d_out, int out_size, void* d_ws, size_t ws_size,
                              hipStream_t stream) {
    const float* x  = (const float*)d_in[0];
    const float* Wq = (const float*)d_in[1];
    const float* bq = (const float*)d_in[2];
    const float* Wk = (const float*)d_in[3];
    const float* bk = (const float*)d_in[4];
    const float* Wv = (const float*)d_in[5];
    const float* bv = (const float*)d_in[6];
    float* z = (float*)d_out;

    // ws (bf16): Q, K, Vtp, W (~48.8 MB, proven). d_out scratch: xt only.
    const size_t qElems   = (size_t)BB * NH * TT * HWP * CID;   // 6,422,528
    const size_t kElems   = (size_t)BB * NH * TP * HWP * CID;   // 8,028,160
    const size_t vtpElems = (size_t)BB * NH * TP * 64 * VSLOT;  // 9,175,040

    u16* Qw  = (u16*)d_ws;
    u16* Kw  = Qw + qElems;
    u16* Vtp = Kw + kElems;
    u16* Wb  = Vtp + vtpElems;
    u16* Xt  = (u16*)d_out;

    {
        const int wtot = NTOT * CC / 2;
        const int kper = 2 * NH * 8 * HWP * 32;
        const int vper = 2 * NH * 8 * 64 * (VSLOT / 2);
        const int prepBlocks = (wtot + kper + vper + 255) / 256;   // 8256
        prep_transpose<<<BB * TT * 8 + prepBlocks, 256, 0, stream>>>(
            x, Xt, Wq, Wk, Wv, Wb, bk, bv, Kw, Vtp);
    }
    // 98 m-tiles x 6 n-tiles, 512 threads; gload_lds staging, fused V write.
    proj_gemm2<<<98 * 6, 512, 0, stream>>>(Xt, Wb, bq, bk, bv, Qw, Kw, Vtp);
    // 16 slabs * 32 t, 4 waves/block, XCD-swizzled; 512 blocks.
    // LDS-shared K/V (gload_lds) — kills the 4x intra-block L1 redundancy.
    attn_mfma4<<<512, 256, 0, stream>>>(x, Qw, Kw, Vtp, z);
}